// Round 6
// baseline (11650.217 us; speedup 1.0000x reference)
//
#include <hip/hip_runtime.h>

#define S_LEN 512
#define HID   50
#define NB    16      // batches per block
#define NT    13      // M tiles of 16 rows: 13*16 = 208 >= 200 gate rows

typedef _Float16 f16x8 __attribute__((ext_vector_type(8)));
typedef float    f32x4 __attribute__((ext_vector_type(4)));

__device__ __forceinline__ float fast_sigmoid(float v) {
    return 1.0f / (1.0f + __expf(-v));
}
__device__ __forceinline__ float fast_tanh(float v) {
    return 1.0f - 2.0f / (__expf(2.0f * v) + 1.0f);
}

// half-index of h[unit u] for batch b inside one h buffer (64 halfs/batch).
// XOR-swizzle the 16B (8-half) block so B-fragment ds_read_b128 spreads
// across banks (unswizzled: 128B batch stride => all lanes same bank set).
__device__ __forceinline__ int hIdx(int b, int u) {
    return b * 64 + ((((u >> 3) ^ (b & 7))) << 3) + (u & 7);
}

// z^T[208pad, 16] = W_ext[208pad, 64pad] @ h^T[64pad, 16] per step, via
// mfma_f32_16x16x32_f16. Gate rows interleaved as packed row = 4*unit+gate
// so C-tile lane layout (col=lane&15=batch, row=4*(lane>>4)+reg) gives each
// lane all 4 gates of ONE (unit,batch) in its 4 acc regs -> gate math and
// c/h update are lane-local. Per-wave persistent regs ~68 (A-frags 32,
// bias/wih 32, c 4) -- inside the allocator's proven ~100-reg comfort zone,
// unlike rounds 1-5 which it spilled (VGPR 76-124, ~800-980us).
__global__ __launch_bounds__(256, 1) void lstm_mfma_kernel(
    const float* __restrict__ x,      // [B, S] (I==1)
    const float* __restrict__ W_ih,   // [200, 1]
    const float* __restrict__ W_hh,   // [200, 50]
    const float* __restrict__ b_ih,   // [200]
    const float* __restrict__ b_hh,   // [200]
    const float* __restrict__ W_fc,   // [1, 50]
    const float* __restrict__ b_fc,   // [1]
    float* __restrict__ out)          // [B]
{
    const int blk  = blockIdx.x;
    const int tid  = threadIdx.x;     // 0..255
    const int wave = tid >> 6;        // 0..3
    const int lane = tid & 63;
    const int bcol = lane & 15;       // batch column within block
    const int grp  = lane >> 4;       // 0..3

    __shared__ __align__(16) float    x_lds[S_LEN][NB];   // 32 KB, x transposed
    __shared__ __align__(16) _Float16 h_lds[2][NB * 64];  // 4 KB, h^T swizzled

    // zero both h buffers (padding units 50..63 MUST be 0; also h0 = 0)
    for (int i = tid; i < 2 * NB * 64; i += 256)
        (&h_lds[0][0])[i] = (_Float16)0.0f;

    // stage x transposed: x_lds[s][b]  (reads coalesced per 16-lane group)
    {
        const int bb  = tid >> 4;     // 0..15
        const int ss0 = tid & 15;
        const float* xrow = x + (size_t)(blk * NB + bb) * S_LEN;
        #pragma unroll
        for (int i = 0; i < 32; ++i) {
            const int s = ss0 + 16 * i;
            x_lds[s][bb] = xrow[s];
        }
    }

    // tile ownership: wave0 -> t 0..3, wave1 -> 4..6, wave2 -> 7..9, wave3 -> 10..12
    const int t0  = (wave == 0) ? 0 : (wave == 1) ? 4 : (wave == 2) ? 7 : 10;
    const int ntl = (wave == 0) ? 4 : 3;

    // A-fragments (W_ext, constant over steps) + per-reg bias/wih.
    // A [16,32] lane layout: row = lane&15, k = 8*grp + e.
    f16x8 afrag[4][2];
    float bias_r[4][4], wih_r[4][4];
    for (int ti = 0; ti < 4; ++ti) {
        if (ti < ntl) {
            const int t    = t0 + ti;
            const int prow = 16 * t + (lane & 15);      // packed row = 4u+g
            const int ua   = prow >> 2;
            const int ga   = prow & 3;
            #pragma unroll
            for (int kc = 0; kc < 2; ++kc) {
                f16x8 fr;
                #pragma unroll
                for (int e = 0; e < 8; ++e) {
                    const int k = 32 * kc + 8 * grp + e;
                    const float wv = (ua < HID && k < HID)
                                   ? W_hh[(ga * HID + ua) * HID + k] : 0.0f;
                    fr[e] = (_Float16)wv;
                }
                afrag[ti][kc] = fr;
            }
            const int uc = 4 * t + grp;                 // unit this lane owns
            #pragma unroll
            for (int r = 0; r < 4; ++r) {               // r == gate index
                if (uc < HID) {
                    const int orow = r * HID + uc;
                    bias_r[ti][r] = b_ih[orow] + b_hh[orow];
                    wih_r[ti][r]  = W_ih[orow];
                } else {
                    bias_r[ti][r] = 0.0f;
                    wih_r[ti][r]  = 0.0f;
                }
            }
        } else {
            #pragma unroll
            for (int kc = 0; kc < 2; ++kc) afrag[ti][kc] = (f16x8)(_Float16)0.0f;
            #pragma unroll
            for (int r = 0; r < 4; ++r) { bias_r[ti][r] = 0.0f; wih_r[ti][r] = 0.0f; }
        }
    }

    float cst[4] = {0.0f, 0.0f, 0.0f, 0.0f};

    __syncthreads();

    for (int s = 0; s < S_LEN; ++s) {
        const _Float16* hcur = h_lds[s & 1];
        _Float16*       hnxt = h_lds[(s & 1) ^ 1];

        // B-fragments: lane reads 8 consecutive units (k), fixed batch col.
        // B [32,16] layout: col = lane&15, k = 8*grp + e.  16B swizzled reads.
        f16x8 bfr[2];
        #pragma unroll
        for (int kc = 0; kc < 2; ++kc) {
            const int blku = (kc * 4 + grp) ^ (bcol & 7);
            bfr[kc] = *reinterpret_cast<const f16x8*>(hcur + bcol * 64 + (blku << 3));
        }
        const float xv = x_lds[s][bcol];

        for (int ti = 0; ti < ntl; ++ti) {
            f32x4 acc;
            #pragma unroll
            for (int r = 0; r < 4; ++r)
                acc[r] = fmaf(xv, wih_r[ti][r], bias_r[ti][r]);
            acc = __builtin_amdgcn_mfma_f32_16x16x32_f16(afrag[ti][0], bfr[0], acc, 0, 0, 0);
            acc = __builtin_amdgcn_mfma_f32_16x16x32_f16(afrag[ti][1], bfr[1], acc, 0, 0, 0);

            // lane owns unit u = 4t+grp, batch bcol; regs = gates i,f,g,o
            const float ig = fast_sigmoid(acc[0]);
            const float fg = fast_sigmoid(acc[1]);
            const float gg = fast_tanh(acc[2]);
            const float og = fast_sigmoid(acc[3]);
            const float c  = fmaf(fg, cst[ti], ig * gg);
            cst[ti] = c;
            const float hv = og * fast_tanh(c);

            const int u = 4 * (t0 + ti) + grp;
            if (u < HID) hnxt[hIdx(bcol, u)] = (_Float16)hv;
        }
        __syncthreads();    // writes to hnxt visible; hcur free for re-write
    }

    // final h is in h_lds[0] (step 511 wrote buffer (511&1)^1 = 0)
    if (tid < NB) {
        const _Float16* hf = h_lds[0];
        float sum = b_fc[0];
        for (int u = 0; u < HID; ++u)
            sum += W_fc[u] * (float)hf[hIdx(tid, u)];
        out[blk * NB + tid] = fast_sigmoid(sum);
    }
}

extern "C" void kernel_launch(void* const* d_in, const int* in_sizes, int n_in,
                              void* d_out, int out_size, void* d_ws, size_t ws_size,
                              hipStream_t stream) {
    const float* x    = (const float*)d_in[0];
    const float* W_ih = (const float*)d_in[1];
    const float* W_hh = (const float*)d_in[2];
    const float* b_ih = (const float*)d_in[3];
    const float* b_hh = (const float*)d_in[4];
    const float* W_fc = (const float*)d_in[5];
    const float* b_fc = (const float*)d_in[6];
    float* out = (float*)d_out;

    lstm_mfma_kernel<<<4096 / NB, 256, 0, stream>>>(x, W_ih, W_hh, b_ih, b_hh,
                                                    W_fc, b_fc, out);
}

// Round 7
// 545.899 us; speedup vs baseline: 21.3413x; 21.3413x over previous
//
#include <hip/hip_runtime.h>

#define S_LEN 512
#define HID   50
#define NB    16      // batches per block

typedef _Float16 f16x8 __attribute__((ext_vector_type(8)));
typedef float    f32x4 __attribute__((ext_vector_type(4)));

__device__ __forceinline__ float fast_sigmoid(float v) {
    return 1.0f / (1.0f + __expf(-v));
}
__device__ __forceinline__ float fast_tanh(float v) {
    return 1.0f - 2.0f / (__expf(2.0f * v) + 1.0f);
}

// half-index of h[unit u] for batch b (64 halfs/batch); XOR-swizzled 16B
// blocks so B-fragment ds_read_b128 spreads across banks.
__device__ __forceinline__ int hIdx(int b, int u) {
    return b * 64 + ((((u >> 3) ^ (b & 7))) << 3) + (u & 7);
}

// Same algorithm as round 6 (verified correct): per step,
// z^T[208,16] = W_ext[208,64] @ h^T[64,16] via mfma_f32_16x16x32_f16 with
// gate rows packed as 4*unit+gate, so each lane's 4 acc regs are the 4
// gates of one (unit,batch) -> lane-local gate math.
// FIX vs round 6: all per-tile state lives in SEPARATELY NAMED arrays
// accessed only with compile-time indices through forceinline lambdas.
// Round 6 indexed afrag[ti] with a runtime loop bound -> scratch (rule:
// runtime-indexed arrays allocate in local memory), giving 22us/step.
__global__ __launch_bounds__(256, 1) void lstm_mfma_kernel(
    const float* __restrict__ x,      // [B, S] (I==1)
    const float* __restrict__ W_ih,   // [200, 1]
    const float* __restrict__ W_hh,   // [200, 50]
    const float* __restrict__ b_ih,   // [200]
    const float* __restrict__ b_hh,   // [200]
    const float* __restrict__ W_fc,   // [1, 50]
    const float* __restrict__ b_fc,   // [1]
    float* __restrict__ out)          // [B]
{
    const int blk  = blockIdx.x;
    const int tid  = threadIdx.x;     // 0..255
    const int wave = tid >> 6;        // 0..3
    const int lane = tid & 63;
    const int bcol = lane & 15;       // batch column
    const int grp  = lane >> 4;       // 0..3

    __shared__ __align__(16) float    x_lds[S_LEN][NB];   // 32 KB
    __shared__ __align__(16) _Float16 h_lds[2][NB * 64];  // 4 KB

    for (int i = tid; i < 2 * NB * 64; i += 256)
        (&h_lds[0][0])[i] = (_Float16)0.0f;               // pads + h0 = 0

    {   // stage x transposed: x_lds[s][b]
        const int bb  = tid >> 4;
        const int ss0 = tid & 15;
        const float* xrow = x + (size_t)(blk * NB + bb) * S_LEN;
        #pragma unroll
        for (int i = 0; i < 32; ++i) {
            const int s = ss0 + 16 * i;
            x_lds[s][bb] = xrow[s];
        }
    }

    // tiles: wave0 -> 0..3, wave1 -> 4..6, wave2 -> 7..9, wave3 -> 10..12
    const int t0  = (wave == 0) ? 0 : (wave == 1) ? 4 : (wave == 2) ? 7 : 10;
    const int ntl = (wave == 0) ? 4 : 3;

    f16x8 af0[2], af1[2], af2[2], af3[2];
    float bi0[4], bi1[4], bi2[4], bi3[4];
    float wi0[4], wi1[4], wi2[4], wi3[4];

    auto load_tile = [&](int t, bool active, f16x8 (&af)[2],
                         float (&bi)[4], float (&wi)[4]) __attribute__((always_inline)) {
        const int prow = 16 * t + (lane & 15);   // packed row = 4*unit+gate
        const int ua = prow >> 2, ga = prow & 3;
        #pragma unroll
        for (int kc = 0; kc < 2; ++kc) {
            f16x8 fr;
            #pragma unroll
            for (int e = 0; e < 8; ++e) {
                const int k = 32 * kc + 8 * grp + e;
                const float wv = (active && ua < HID && k < HID)
                               ? W_hh[(ga * HID + ua) * HID + k] : 0.0f;
                fr[e] = (_Float16)wv;
            }
            af[kc] = fr;
        }
        const int uc = 4 * t + grp;              // unit this lane owns
        #pragma unroll
        for (int r = 0; r < 4; ++r) {            // r == gate
            if (active && uc < HID) {
                const int orow = r * HID + uc;
                bi[r] = b_ih[orow] + b_hh[orow];
                wi[r] = W_ih[orow];
            } else { bi[r] = 0.0f; wi[r] = 0.0f; }
        }
    };
    load_tile(t0 + 0, true,      af0, bi0, wi0);
    load_tile(t0 + 1, true,      af1, bi1, wi1);
    load_tile(t0 + 2, true,      af2, bi2, wi2);
    load_tile(t0 + 3, ntl == 4,  af3, bi3, wi3);

    float cst0 = 0.0f, cst1 = 0.0f, cst2 = 0.0f, cst3 = 0.0f;

    __syncthreads();

    for (int s = 0; s < S_LEN; ++s) {
        const _Float16* hcur = h_lds[s & 1];
        _Float16*       hnxt = h_lds[(s & 1) ^ 1];

        const int swz = bcol & 7;
        const f16x8 bfr0 = *reinterpret_cast<const f16x8*>(
            hcur + bcol * 64 + ((grp ^ swz) << 3));
        const f16x8 bfr1 = *reinterpret_cast<const f16x8*>(
            hcur + bcol * 64 + (((4 + grp) ^ swz) << 3));
        const float xv = x_lds[s][bcol];

        auto do_tile = [&](int t, const f16x8 (&af)[2], const float (&bi)[4],
                           const float (&wi)[4], float& cst) __attribute__((always_inline)) {
            f32x4 acc;
            #pragma unroll
            for (int r = 0; r < 4; ++r) acc[r] = fmaf(xv, wi[r], bi[r]);
            acc = __builtin_amdgcn_mfma_f32_16x16x32_f16(af[0], bfr0, acc, 0, 0, 0);
            acc = __builtin_amdgcn_mfma_f32_16x16x32_f16(af[1], bfr1, acc, 0, 0, 0);
            const float ig = fast_sigmoid(acc[0]);
            const float fg = fast_sigmoid(acc[1]);
            const float gg = fast_tanh(acc[2]);
            const float og = fast_sigmoid(acc[3]);
            cst = fmaf(fg, cst, ig * gg);
            const float hv = og * fast_tanh(cst);
            const int u = 4 * t + grp;
            if (u < HID) hnxt[hIdx(bcol, u)] = (_Float16)hv;
        };
        do_tile(t0 + 0, af0, bi0, wi0, cst0);
        do_tile(t0 + 1, af1, bi1, wi1, cst1);
        do_tile(t0 + 2, af2, bi2, wi2, cst2);
        if (ntl == 4) do_tile(t0 + 3, af3, bi3, wi3, cst3);

        __syncthreads();
    }

    // final h is in h_lds[0] (step 511 wrote buffer 0)
    if (tid < NB) {
        const _Float16* hf = h_lds[0];
        float sum = b_fc[0];
        for (int u = 0; u < HID; ++u)
            sum += W_fc[u] * (float)hf[hIdx(tid, u)];
        out[blk * NB + tid] = fast_sigmoid(sum);
    }
}

extern "C" void kernel_launch(void* const* d_in, const int* in_sizes, int n_in,
                              void* d_out, int out_size, void* d_ws, size_t ws_size,
                              hipStream_t stream) {
    const float* x    = (const float*)d_in[0];
    const float* W_ih = (const float*)d_in[1];
    const float* W_hh = (const float*)d_in[2];
    const float* b_ih = (const float*)d_in[3];
    const float* b_hh = (const float*)d_in[4];
    const float* W_fc = (const float*)d_in[5];
    const float* b_fc = (const float*)d_in[6];
    float* out = (float*)d_out;

    lstm_mfma_kernel<<<4096 / NB, 256, 0, stream>>>(x, W_ih, W_hh, b_ih, b_hh,
                                                    W_fc, b_fc, out);
}

// Round 10
// 381.378 us; speedup vs baseline: 30.5477x; 1.4314x over previous
//
#include <hip/hip_runtime.h>

#define S_LEN 512
#define HID   50
#define NB    8       // batches per block -> 512 blocks = 2 blocks/CU

typedef _Float16 f16x8 __attribute__((ext_vector_type(8)));
typedef float    f32x4 __attribute__((ext_vector_type(4)));

#define LOG2E 1.44269504088896340736f

// TRANS ops via compiler intrinsics (NOT inline asm): the CDNA trans-use
// hazard (1 wait state before consuming v_exp/v_rcp results) is only
// inserted by the compiler when IT emits the op. Round 9's inline-asm
// versions hid the instruction class from the hazard recognizer ->
// stale-register reads -> absmax 0.205.
__device__ __forceinline__ float ex2(float a) {
#if __has_builtin(__builtin_amdgcn_exp2f)
    return __builtin_amdgcn_exp2f(a);
#else
    return __expf(0.69314718055994531f * a);   // e^(ln2*a) = 2^a
#endif
}
__device__ __forceinline__ float rcpf(float a) {
#if __has_builtin(__builtin_amdgcn_rcpf)
    return __builtin_amdgcn_rcpf(a);
#else
    return 1.0f / a;
#endif
}
// sigmoid(z) where a = -log2e * z   (scale folded into weights)
__device__ __forceinline__ float sig_s(float a)  { return rcpf(1.0f + ex2(a)); }
// tanh(z) where a = 2*log2e * z     (scale folded into weights)
__device__ __forceinline__ float tanh_s(float a) { return fmaf(-2.0f, rcpf(1.0f + ex2(a)), 1.0f); }

// half-index of h[unit u] for batch b (64 halfs/batch); XOR-swizzled 16B
// blocks so B-fragment ds_read_b128 spreads across banks.
__device__ __forceinline__ int hIdx(int b, int u) {
    return b * 64 + ((((u >> 3) ^ (b & 7))) << 3) + (u & 7);
}

// MFMA LSTM (round 10 = round 8 structure + intrinsic trans ops):
//  - z^T[208,16] = W_ext[208,64] @ hext^T[64,16] per step via
//    mfma_f32_16x16x32_f16; packed gate rows 4*unit+gate make each lane's
//    4 acc regs = the 4 gates of one (unit,batch) -> lane-local gate math.
//  - x_t and bias folded into K: hext[50]=x_t, hext[51]=1.0; A rows carry
//    wih and bias. No per-lane bias/wih arrays -> persistent state ~45
//    VGPRs, nothing to spill (rounds 1-7 all lost to spills).
//  - gate rows pre-scaled by -log2e (i,f,o) / +2log2e (g): activation =
//    v_exp + add + v_rcp only.
//  - NB=8 -> 512 blocks = 2 blocks/CU so co-resident blocks hide each
//    other's MFMA/LDS/trans latency across the barrier.
__global__ __launch_bounds__(256, 2) void lstm_mfma_kernel(
    const float* __restrict__ x,      // [B, S] (I==1)
    const float* __restrict__ W_ih,   // [200, 1]
    const float* __restrict__ W_hh,   // [200, 50]
    const float* __restrict__ b_ih,   // [200]
    const float* __restrict__ b_hh,   // [200]
    const float* __restrict__ W_fc,   // [1, 50]
    const float* __restrict__ b_fc,   // [1]
    float* __restrict__ out)          // [B]
{
    const int blk  = blockIdx.x;
    const int tid  = threadIdx.x;     // 0..255
    const int wave = tid >> 6;        // 0..3
    const int lane = tid & 63;
    const int bcol = lane & 15;       // MFMA N col; cols 8..15 mirror 0..7
    const int brd  = bcol & 7;        // real batch this col reads
    const int grp  = lane >> 4;       // 0..3

    __shared__ __align__(16) float    x_lds[S_LEN][NB];   // 16 KB
    __shared__ __align__(16) _Float16 h_lds[2][NB * 64];  // 2 KB

    // ---- zero h buffers (pads 52..63 must stay 0 forever) ----
    for (int i = tid; i < 2 * NB * 64; i += 256)
        (&h_lds[0][0])[i] = (_Float16)0.0f;
    __syncthreads();   // before targeted writes below overwrite slots

    // ---- stage x transposed: x_lds[s][b] (coalesced: 32 lanes per batch row)
    {
        const int bb  = tid >> 5;     // 0..7
        const int ss0 = tid & 31;
        const float* xrow = x + (size_t)(blk * NB + bb) * S_LEN;
        #pragma unroll
        for (int i = 0; i < 16; ++i) {
            const int s = ss0 + 32 * i;
            x_lds[s][bb] = xrow[s];
        }
    }
    // seed K-extension slots: h[50] = x_0, h[51] = 1.0 (both buffers' [51])
    if (tid < NB) {
        h_lds[0][hIdx(tid, 50)] = (_Float16)x[(size_t)(blk * NB + tid) * S_LEN];
        h_lds[0][hIdx(tid, 51)] = (_Float16)1.0f;
        h_lds[1][hIdx(tid, 51)] = (_Float16)1.0f;
    }

    // tiles: wave0 -> 0..3, wave1 -> 4..6, wave2 -> 7..9, wave3 -> 10..12
    const int t0  = (wave == 0) ? 0 : (wave == 1) ? 4 : (wave == 2) ? 7 : 10;
    const int ntl = (wave == 0) ? 4 : 3;

    f16x8 af0[2], af1[2], af2[2], af3[2];

    // A row (packed prow = 4*unit+gate) over extended K:
    //   k<50 -> W_hh[orow][k]; k==50 -> W_ih[orow]; k==51 -> b_ih+b_hh; else 0
    // whole row scaled by -log2e (gates i,f,o) or +2log2e (gate g).
    auto load_tile = [&](int t, bool active, f16x8 (&af)[2]) __attribute__((always_inline)) {
        const int prow = 16 * t + (lane & 15);
        const int ua = prow >> 2, ga = prow & 3;
        const float sc = (ga == 2) ? (2.0f * LOG2E) : (-LOG2E);
        const int orow = ga * HID + ua;
        #pragma unroll
        for (int kc = 0; kc < 2; ++kc) {
            f16x8 fr;
            #pragma unroll
            for (int e = 0; e < 8; ++e) {
                const int k = 32 * kc + 8 * grp + e;
                float wv = 0.0f;
                if (active && ua < HID) {
                    if (k < HID)       wv = W_hh[orow * HID + k];
                    else if (k == 50)  wv = W_ih[orow];
                    else if (k == 51)  wv = b_ih[orow] + b_hh[orow];
                }
                fr[e] = (_Float16)(sc * wv);
            }
            af[kc] = fr;
        }
    };
    load_tile(t0 + 0, true,     af0);
    load_tile(t0 + 1, true,     af1);
    load_tile(t0 + 2, true,     af2);
    load_tile(t0 + 3, ntl == 4, af3);

    // hoisted per-tile write index + guard, and B-frag offsets
    const int u0 = 4 * (t0 + 0) + grp, u1 = 4 * (t0 + 1) + grp;
    const int u2 = 4 * (t0 + 2) + grp, u3 = 4 * (t0 + 3) + grp;
    const bool wr_ok = (bcol < NB);
    const bool w0 = wr_ok && (u0 < HID), w1 = wr_ok && (u1 < HID);
    const bool w2 = wr_ok && (u2 < HID), w3 = wr_ok && (u3 < HID) && (ntl == 4);
    const int i0 = hIdx(brd, u0 < 64 ? u0 : 0), i1 = hIdx(brd, u1 < 64 ? u1 : 0);
    const int i2 = hIdx(brd, u2 < 64 ? u2 : 0), i3 = hIdx(brd, u3 < 64 ? u3 : 0);
    const int off0 = brd * 64 + ((grp ^ brd) << 3);
    const int off1 = brd * 64 + (((4 + grp) ^ brd) << 3);

    float cst0 = 0.0f, cst1 = 0.0f, cst2 = 0.0f, cst3 = 0.0f;

    __syncthreads();

    for (int s = 0; s < S_LEN; ++s) {
        const _Float16* hcur = h_lds[s & 1];
        _Float16*       hnxt = h_lds[(s & 1) ^ 1];

        const f16x8 bfr0 = *reinterpret_cast<const f16x8*>(hcur + off0);
        const f16x8 bfr1 = *reinterpret_cast<const f16x8*>(hcur + off1);

        auto do_tile = [&](const f16x8 (&af)[2], float& cst,
                           int widx, bool wr) __attribute__((always_inline)) {
            f32x4 acc = {0.0f, 0.0f, 0.0f, 0.0f};
            acc = __builtin_amdgcn_mfma_f32_16x16x32_f16(af[0], bfr0, acc, 0, 0, 0);
            acc = __builtin_amdgcn_mfma_f32_16x16x32_f16(af[1], bfr1, acc, 0, 0, 0);
            const float ig = sig_s(acc[0]);
            const float fg = sig_s(acc[1]);
            const float gg = tanh_s(acc[2]);
            const float og = sig_s(acc[3]);
            cst = fmaf(fg, cst, ig * gg);
            const float hv = og * tanh_s(cst * (2.0f * LOG2E));
            if (wr) hnxt[widx] = (_Float16)hv;
        };
        do_tile(af0, cst0, i0, w0);
        do_tile(af1, cst1, i1, w1);
        do_tile(af2, cst2, i2, w2);
        if (ntl == 4) do_tile(af3, cst3, i3, w3);

        // feed next step's x into the K-extension slot (wave1: light duty)
        if (wave == 1 && lane < NB && s + 1 < S_LEN)
            hnxt[hIdx(lane, 50)] = (_Float16)x_lds[s + 1][lane];

        __syncthreads();
    }

    // final h is in h_lds[0] (step 511 wrote buffer 0)
    if (tid < NB) {
        const _Float16* hf = h_lds[0];
        float sum = b_fc[0];
        for (int u = 0; u < HID; ++u)
            sum += W_fc[u] * (float)hf[hIdx(tid, u)];
        out[blk * NB + tid] = 1.0f / (1.0f + __expf(-sum));
    }
}

extern "C" void kernel_launch(void* const* d_in, const int* in_sizes, int n_in,
                              void* d_out, int out_size, void* d_ws, size_t ws_size,
                              hipStream_t stream) {
    const float* x    = (const float*)d_in[0];
    const float* W_ih = (const float*)d_in[1];
    const float* W_hh = (const float*)d_in[2];
    const float* b_ih = (const float*)d_in[3];
    const float* b_hh = (const float*)d_in[4];
    const float* W_fc = (const float*)d_in[5];
    const float* b_fc = (const float*)d_in[6];
    float* out = (float*)d_out;

    lstm_mfma_kernel<<<4096 / NB, 256, 0, stream>>>(x, W_ih, W_hh, b_ih, b_hh,
                                                    W_fc, b_fc, out);
}

// Round 12
// 283.053 us; speedup vs baseline: 41.1592x; 1.3474x over previous
//
#include <hip/hip_runtime.h>

#define S_LEN 512
#define HID   50
#define NB    16      // real batches per block (all 16 MFMA N-cols used)
#define NTHR  832     // 13 waves; wave w owns M-tile w (13*16=208 >= 200 rows)

typedef _Float16 f16x8 __attribute__((ext_vector_type(8)));
typedef float    f32x4 __attribute__((ext_vector_type(4)));

#define LOG2E 1.44269504088896340736f

// TRANS ops via compiler intrinsics (NOT inline asm): round 9 proved the
// hazard recognizer must see the trans op class (asm version -> stale reads).
__device__ __forceinline__ float ex2(float a) {
#if __has_builtin(__builtin_amdgcn_exp2f)
    return __builtin_amdgcn_exp2f(a);
#else
    return __expf(0.69314718055994531f * a);
#endif
}
__device__ __forceinline__ float rcpf(float a) {
#if __has_builtin(__builtin_amdgcn_rcpf)
    return __builtin_amdgcn_rcpf(a);
#else
    return 1.0f / a;
#endif
}
// sigmoid(z) with a = -log2e*z folded into weights
__device__ __forceinline__ float sig_s(float a)  { return rcpf(1.0f + ex2(a)); }
// tanh(z) with a = 2*log2e*z folded into weights
__device__ __forceinline__ float tanh_s(float a) { return fmaf(-2.0f, rcpf(1.0f + ex2(a)), 1.0f); }

// half-index of h[unit u] for batch b (64 halfs/batch); XOR-swizzled 16B
// blocks. R10 measured conflicts ~1.75/block-step with this -> near-optimal.
__device__ __forceinline__ int hIdx(int b, int u) {
    return b * 64 + ((((u >> 3) ^ (b & 7))) << 3) + (u & 7);
}

// MFMA LSTM round 11. vs round 10 (381us, NB=8, 4 waves x ~3 tiles, mirror
// cols): NB=16 uses all 16 MFMA N-columns as REAL batches -> per-CU per-step
// work halves (13 tiles serve 16 batches, was 26). 13 waves, each owning
// EXACTLY one M-tile: balanced skew, per-wave state ~25 VGPRs. 256 blocks =
// 1 block/CU. Everything else (K-folded x/bias, pre-scaled gate rows,
// intrinsic trans) carried over from the verified round 10.
__global__ __launch_bounds__(NTHR, 1) void lstm_mfma_kernel(
    const float* __restrict__ x,      // [B, S] (I==1)
    const float* __restrict__ W_ih,   // [200, 1]
    const float* __restrict__ W_hh,   // [200, 50]
    const float* __restrict__ b_ih,   // [200]
    const float* __restrict__ b_hh,   // [200]
    const float* __restrict__ W_fc,   // [1, 50]
    const float* __restrict__ b_fc,   // [1]
    float* __restrict__ out)          // [B]
{
    const int blk  = blockIdx.x;
    const int tid  = threadIdx.x;     // 0..831
    const int wave = tid >> 6;        // 0..12 == owned M-tile
    const int lane = tid & 63;
    const int bcol = lane & 15;       // real batch column 0..15
    const int grp  = lane >> 4;       // 0..3

    __shared__ __align__(16) float    x_lds[S_LEN][NB];   // 32 KB
    __shared__ __align__(16) _Float16 h_lds[2][NB * 64];  // 4 KB

    // ---- zero h buffers (pads 52..63 must stay 0 forever) ----
    for (int i = tid; i < 2 * NB * 64; i += NTHR)
        (&h_lds[0][0])[i] = (_Float16)0.0f;
    __syncthreads();

    // ---- stage x transposed: x_lds[s][b] (waves 0..7; coalesced 32/row) ----
    if (tid < 512) {
        const int bb  = tid >> 5;     // 0..15
        const int ss0 = tid & 31;
        const float* xrow = x + (size_t)(blk * NB + bb) * S_LEN;
        #pragma unroll
        for (int i = 0; i < 16; ++i) {
            const int s = ss0 + 32 * i;
            x_lds[s][bb] = xrow[s];
        }
    }
    // seed K-extension slots: h[50] = x_0, h[51] = 1.0
    if (tid < NB) {
        h_lds[0][hIdx(tid, 50)] = (_Float16)x[(size_t)(blk * NB + tid) * S_LEN];
        h_lds[0][hIdx(tid, 51)] = (_Float16)1.0f;
        h_lds[1][hIdx(tid, 51)] = (_Float16)1.0f;
    }

    // ---- this wave's A fragments (packed row = 4*unit+gate, extended K) ----
    //   k<50 -> W_hh[orow][k]; k==50 -> W_ih[orow]; k==51 -> bias; else 0
    //   rows pre-scaled by -log2e (i,f,o) / +2log2e (g)
    f16x8 af0, af1;
    {
        const int prow = 16 * wave + (lane & 15);
        const int ua = prow >> 2, ga = prow & 3;
        const float sc = (ga == 2) ? (2.0f * LOG2E) : (-LOG2E);
        const int orow = ga * HID + ua;
        #pragma unroll
        for (int kc = 0; kc < 2; ++kc) {
            f16x8 fr;
            #pragma unroll
            for (int e = 0; e < 8; ++e) {
                const int k = 32 * kc + 8 * grp + e;
                float wv = 0.0f;
                if (ua < HID) {
                    if (k < HID)       wv = W_hh[orow * HID + k];
                    else if (k == 50)  wv = W_ih[orow];
                    else if (k == 51)  wv = b_ih[orow] + b_hh[orow];
                }
                fr[e] = (_Float16)(sc * wv);
            }
            if (kc == 0) af0 = fr; else af1 = fr;
        }
    }

    // hoisted write index/guard and B-frag LDS offsets
    const int u   = 4 * wave + grp;               // unit this lane owns
    const bool wr = (u < HID);
    const int widx = hIdx(bcol, u < 64 ? u : 0);
    const int off0 = bcol * 64 + ((grp ^ (bcol & 7)) << 3);
    const int off1 = bcol * 64 + (((4 + grp) ^ (bcol & 7)) << 3);
    const bool xfeed = (wave == 12) && (lane < NB);

    float cst = 0.0f;

    __syncthreads();

    for (int s = 0; s < S_LEN; ++s) {
        const _Float16* hcur = h_lds[s & 1];
        _Float16*       hnxt = h_lds[(s & 1) ^ 1];

        const f16x8 bfr0 = *reinterpret_cast<const f16x8*>(hcur + off0);
        const f16x8 bfr1 = *reinterpret_cast<const f16x8*>(hcur + off1);

        f32x4 acc = {0.0f, 0.0f, 0.0f, 0.0f};
        acc = __builtin_amdgcn_mfma_f32_16x16x32_f16(af0, bfr0, acc, 0, 0, 0);
        acc = __builtin_amdgcn_mfma_f32_16x16x32_f16(af1, bfr1, acc, 0, 0, 0);

        const float ig = sig_s(acc[0]);
        const float fg = sig_s(acc[1]);
        const float gg = tanh_s(acc[2]);
        const float og = sig_s(acc[3]);
        cst = fmaf(fg, cst, ig * gg);
        const float hv = og * tanh_s(cst * (2.0f * LOG2E));
        if (wr) hnxt[widx] = (_Float16)hv;

        // feed next step's x into the K-extension slot (wave 12: lightest)
        if (xfeed && s + 1 < S_LEN)
            hnxt[hIdx(lane, 50)] = (_Float16)x_lds[s + 1][lane];

        __syncthreads();
    }

    // final h is in h_lds[0] (step 511 wrote buffer 0)
    if (tid < NB) {
        const _Float16* hf = h_lds[0];
        float sum = b_fc[0];
        for (int uu = 0; uu < HID; ++uu)
            sum += W_fc[uu] * (float)hf[hIdx(tid, uu)];
        out[blk * NB + tid] = 1.0f / (1.0f + __expf(-sum));
    }
}

extern "C" void kernel_launch(void* const* d_in, const int* in_sizes, int n_in,
                              void* d_out, int out_size, void* d_ws, size_t ws_size,
                              hipStream_t stream) {
    const float* x    = (const float*)d_in[0];
    const float* W_ih = (const float*)d_in[1];
    const float* W_hh = (const float*)d_in[2];
    const float* b_ih = (const float*)d_in[3];
    const float* b_hh = (const float*)d_in[4];
    const float* W_fc = (const float*)d_in[5];
    const float* b_fc = (const float*)d_in[6];
    float* out = (float*)d_out;

    lstm_mfma_kernel<<<4096 / NB, NTHR, 0, stream>>>(x, W_ih, W_hh, b_ih, b_hh,
                                                     W_fc, b_fc, out);
}